// Round 5
// baseline (818.810 us; speedup 1.0000x reference)
//
#include <hip/hip_runtime.h>
#include <hip/hip_bf16.h>

// Problem constants
#define D_IN   4096
#define D_OUT  11008
#define NB     32
#define M_ROWS 8192
#define KP     4224          // 4096 + 32 (xsum) + 96 (pad) = 66*64 (3-tile unroll)
#define NTILES 66

// GEMM tiling: 256x128 tile, BK=64, 8 waves (4m x 2n), 2 phases per K-tile,
// triple-buffered LDS (3 x 48 KB = 144 KB)
#define BM  256
#define BN  128
#define NBM 32               // 8192/256
#define NBN 86               // 11008/128

typedef __attribute__((ext_vector_type(4))) float f32x4;
typedef __attribute__((ext_vector_type(8))) short bf16x8;

static __device__ __forceinline__ unsigned short f2bf(float f) {
  unsigned int u = __float_as_uint(f);
  unsigned int lsb = (u >> 16) & 1u;
  u += 0x7fffu + lsb;
  return (unsigned short)(u >> 16);
}

// ---------------------------------------------------------------------------
// Prepass A: x f32 [M][4096] -> A bf16 [M][4224]
__global__ void prep_a_kernel(const float* __restrict__ x,
                              unsigned short* __restrict__ A) {
  const int m = blockIdx.x;
  const int t = threadIdx.x;
  const float* xr = x + (size_t)m * D_IN;
  unsigned short* Ar = A + (size_t)m * KP;
  __shared__ float psum[1024];
#pragma unroll
  for (int i = 0; i < 4; ++i) {
    const int c4 = i * 256 + t;
    const float4 v = ((const float4*)xr)[c4];
    ushort4 o;
    o.x = f2bf(v.x); o.y = f2bf(v.y); o.z = f2bf(v.z); o.w = f2bf(v.w);
    ((ushort4*)Ar)[c4] = o;
    psum[c4] = v.x + v.y + v.z + v.w;
  }
  __syncthreads();
  if (t < 32) {
    float s = 0.f;
    const int base = t * 32;
#pragma unroll
    for (int j = 0; j < 32; ++j) s += psum[base + j];
    Ar[D_IN + t] = f2bf(s);
  } else if (t < 128) {
    Ar[D_IN + t] = 0;                       // zero pad cols 4128..4223
  }
}

// Prepass B (proven): w int32 [32][128][11008] -> Bt bf16 [11008][4224]
__global__ void prep_b_kernel(const int* __restrict__ w,
                              const float* __restrict__ scaler,
                              unsigned short* __restrict__ Bt) {
  const int k0 = blockIdx.x * 64;
  const int n0 = blockIdx.y * 64;
  const int s  = k0 >> 7;
  const int t  = threadIdx.x;
  __shared__ unsigned short lds[64][66];
  {
    const int nl = t & 63;
    const int kb = t >> 6;
    const float sc = scaler[(size_t)s * D_OUT + n0 + nl];
#pragma unroll
    for (int i = 0; i < 16; ++i) {
      const int kl = i * 4 + kb;
      const int wv = w[(size_t)(k0 + kl) * D_OUT + n0 + nl];
      lds[kl][nl] = f2bf((float)wv * sc);
    }
  }
  __syncthreads();
  {
    const int kl = t & 63;
    const int nb = t >> 6;
#pragma unroll
    for (int i = 0; i < 16; ++i) {
      const int nl = i * 4 + nb;
      Bt[(size_t)(n0 + nl) * KP + k0 + kl] = lds[kl][nl];
    }
  }
}

// Fill Bt cols 4096..4223: 32 of -zp, 96 zero. 2 n-rows per 256-thr block.
__global__ void prep_zp_kernel(const float* __restrict__ zp,
                               unsigned short* __restrict__ Bt) {
  const int t = threadIdx.x;
  const int n = blockIdx.x * 2 + (t >> 7);
  const int kk = t & 127;
  const float v = (kk < NB) ? -zp[(size_t)kk * D_OUT + n] : 0.f;
  Bt[(size_t)n * KP + D_IN + kk] = f2bf(v);
}

// ---------------------------------------------------------------------------
// 256x128 GEMM, 2 phases/K-tile, triple-buffered LDS, counted vmcnt(6).
// Per phase: 16 MFMA + 3 stage-ops + 4..12 ds_read_b128 + 2 barriers — same
// density as the proven round-2 schedule; tail 10.4% -> 2.3% (2752 blocks).
#define BAR()  __builtin_amdgcn_s_barrier()
#define PRIO1() __builtin_amdgcn_s_setprio(1)
#define PRIO0() __builtin_amdgcn_s_setprio(0)
#define VMW6() asm volatile("s_waitcnt vmcnt(6)" ::: "memory")
#define VMW0() asm volatile("s_waitcnt vmcnt(0)" ::: "memory")

// LDS map (ushort units): buf k at k*24576; A region 16384 (256x64), then
// B region 8192 (128x64). 3 bufs = 73728 ushorts = 144 KiB.
#define BUFO(k) ((k) * 24576)

// Stage quarter q (64 rows x 64 cols) of A-tile at column kb into buf.
#define STQA(buf, q, kb)                                                       \
  do {                                                                         \
    const unsigned short* gp_ = ApS + (size_t)(q) * 64 * KP + (kb);            \
    unsigned short* lp_ = smem + BUFO(buf) + (q) * 4096 + (tid >> 6) * 512;    \
    __builtin_amdgcn_global_load_lds(                                          \
        (const __attribute__((address_space(1))) void*)gp_,                    \
        (__attribute__((address_space(3))) void*)lp_, 16, 0, 0);               \
  } while (0)

// Stage quarter q (q in {0,1}) of B-tile at column kb into buf.
#define STQB(buf, q, kb)                                                       \
  do {                                                                         \
    const unsigned short* gp_ = BpS + (size_t)(q) * 64 * KP + (kb);            \
    unsigned short* lp_ = smem + BUFO(buf) + 16384 + (q) * 4096 +              \
                          (tid >> 6) * 512;                                    \
    __builtin_amdgcn_global_load_lds(                                          \
        (const __attribute__((address_space(1))) void*)gp_,                    \
        (__attribute__((address_space(3))) void*)lp_, 16, 0, 0);               \
  } while (0)

// A fragments: wave rows wm*64 .. +63, 4 m-frags x 2 K-halves.
#define RD_AF(buf)                                                             \
  do {                                                                         \
    _Pragma("unroll") for (int mf = 0; mf < 4; ++mf) {                         \
      const int ro = BUFO(buf) + (wm * 64 + mf * 16 + l15) * 64;               \
      af[0][mf] = *(const bf16x8*)(smem + ro + sg0);                           \
      af[1][mf] = *(const bf16x8*)(smem + ro + sg1);                           \
    }                                                                          \
  } while (0)

// B fragments for n-half NH (2 of 4 n-frags).
#define RD_BG(buf, NH, BG)                                                     \
  do {                                                                         \
    _Pragma("unroll") for (int nf = 0; nf < 2; ++nf) {                         \
      const int ro = BUFO(buf) + 16384 +                                       \
                     (wn * 64 + ((NH) * 2 + nf) * 16 + l15) * 64;              \
      BG[0][nf] = *(const bf16x8*)(smem + ro + sg0);                           \
      BG[1][nf] = *(const bf16x8*)(smem + ro + sg1);                           \
    }                                                                          \
  } while (0)

// 16 MFMA: 4 m-frags x 2 n-frags x 2 chained K-halves.
#define MM(NH, BG)                                                             \
  do {                                                                         \
    _Pragma("unroll") for (int mf = 0; mf < 4; ++mf)                           \
    _Pragma("unroll") for (int nf = 0; nf < 2; ++nf) {                         \
      f32x4 c = acc[mf][(NH) * 2 + nf];                                        \
      c = __builtin_amdgcn_mfma_f32_16x16x32_bf16(af[0][mf], BG[0][nf], c, 0, 0, 0); \
      c = __builtin_amdgcn_mfma_f32_16x16x32_bf16(af[1][mf], BG[1][nf], c, 0, 0, 0); \
      acc[mf][(NH) * 2 + nf] = c;                                              \
    }                                                                          \
  } while (0)

// One K-tile: compute from buf BT; optionally stage tile at col KB2 into BS.
// LASTW = trailing wait (VMW6 steady state; VMW0/none at the tail).
#define TILE_STEP(BT, BS, KB2, DOSTAGE, LASTW)                                 \
  do {                                                                         \
    RD_AF(BT); RD_BG(BT, 0, bg0);                                              \
    if (DOSTAGE) { STQA(BS, 0, KB2); STQA(BS, 1, KB2); STQA(BS, 2, KB2); }     \
    BAR(); PRIO1(); MM(0, bg0); PRIO0(); BAR();                                \
    RD_BG(BT, 1, bg1);                                                         \
    if (DOSTAGE) { STQA(BS, 3, KB2); STQB(BS, 0, KB2); STQB(BS, 1, KB2); }     \
    BAR(); PRIO1(); MM(1, bg1); PRIO0();                                       \
    LASTW;                                                                     \
    BAR();                                                                     \
  } while (0)

__global__ __launch_bounds__(512, 2) void gemm3_kernel(
    const unsigned short* __restrict__ A,
    const unsigned short* __restrict__ B,
    float* __restrict__ C) {
  __shared__ unsigned short smem[73728];   // 144 KiB, 3 bufs
  const int tid  = threadIdx.x;
  const int lane = tid & 63;
  const int w    = tid >> 6;
  const int wm   = w >> 1;                 // 0..3  (rows wm*64)
  const int wn   = w & 1;                  // 0..1  (cols wn*64)
  const int l15  = lane & 15;
  const int g    = lane >> 4;

  // XCD-aware bijective swizzle (nwg = 2752, %8 == 0; cpx = 344 = 4 M-rows)
  const int bid = blockIdx.x;
  const int swz = (bid & 7) * ((NBM * NBN) >> 3) + (bid >> 3);
  const int tm = swz / NBN;
  const int tn = swz - tm * NBN;
  const size_t m0 = (size_t)tm * BM;
  const size_t n0 = (size_t)tn * BN;

  // Staging source: row = q*64 + (tid>>3); source granule = (tid&7)^(row&7)
  const int srow = tid >> 3;
  const int sgr  = (tid & 7) ^ (srow & 7);
  const unsigned short* ApS = A + (m0 + srow) * KP + sgr * 8;
  const unsigned short* BpS = B + (n0 + srow) * KP + sgr * 8;

  // ds_read granule offsets (swizzled): ks=0 granule g, ks=1 granule 4+g
  const int sg0 = ((g) ^ (lane & 7)) * 8;
  const int sg1 = ((4 + g) ^ (lane & 7)) * 8;

  f32x4 acc[4][4];
#pragma unroll
  for (int i = 0; i < 4; ++i)
#pragma unroll
    for (int j = 0; j < 4; ++j) acc[i][j] = (f32x4){0.f, 0.f, 0.f, 0.f};
  bf16x8 af[2][4], bg0[2][2], bg1[2][2];

  // Prologue: stage tile 0 -> buf0, tile 1 -> buf1; wait for tile 0.
  STQA(0, 0, 0); STQA(0, 1, 0); STQA(0, 2, 0); STQA(0, 3, 0);
  STQB(0, 0, 0); STQB(0, 1, 0);
  STQA(1, 0, 64); STQA(1, 1, 64); STQA(1, 2, 64); STQA(1, 3, 64);
  STQB(1, 0, 64); STQB(1, 1, 64);
  VMW6();
  BAR();

  // Main: 21 iterations x 3 K-tiles (tiles 0..62), staging tiles 2..64.
  // Tile t in buf (t%3); stage target buf (t+2)%3 held tile t-1 whose last
  // read was the immediately preceding phase — safe after its end barrier.
#pragma unroll 1
  for (int i = 0; i < 21; ++i) {
    const int kb = 3 * i * 64;
    TILE_STEP(0, 2, kb + 128, true, VMW6());
    TILE_STEP(1, 0, kb + 192, true, VMW6());
    TILE_STEP(2, 1, kb + 256, true, VMW6());
  }
  // Peeled tail: tiles 63 (buf0, stages 65), 64 (buf1, drain), 65 (buf2).
  TILE_STEP(0, 2, 65 * 64, true, VMW6());
  TILE_STEP(1, 0, 0, false, VMW0());
  TILE_STEP(2, 0, 0, false, );

  // C write: col = lane&15, row = (lane>>4)*4 + j (m89-verified layout).
#pragma unroll
  for (int mf = 0; mf < 4; ++mf) {
#pragma unroll
    for (int nf = 0; nf < 4; ++nf) {
      const size_t row = m0 + wm * 64 + mf * 16 + (g << 2);
      const size_t col = n0 + wn * 64 + nf * 16 + l15;
      float* Cp = C + row * D_OUT + col;
#pragma unroll
      for (int j = 0; j < 4; ++j) Cp[(size_t)j * D_OUT] = acc[mf][nf][j];
    }
  }
}

// ---------------------------------------------------------------------------
extern "C" void kernel_launch(void* const* d_in, const int* in_sizes, int n_in,
                              void* d_out, int out_size, void* d_ws, size_t ws_size,
                              hipStream_t stream) {
  const float* x      = (const float*)d_in[0];
  const int*   wq     = (const int*)  d_in[1];
  const float* scaler = (const float*)d_in[2];
  const float* zp     = (const float*)d_in[3];
  float* out = (float*)d_out;

  // Workspace: A bf16 [8192][4224] + Bt bf16 [11008][4224] = 162.2 MB
  unsigned short* A  = (unsigned short*)d_ws;
  unsigned short* Bt = A + (size_t)M_ROWS * KP;

  prep_a_kernel<<<M_ROWS, 256, 0, stream>>>(x, A);
  prep_b_kernel<<<dim3(D_IN / 64, D_OUT / 64), 256, 0, stream>>>(wq, scaler, Bt);
  prep_zp_kernel<<<D_OUT / 2, 256, 0, stream>>>(zp, Bt);
  gemm3_kernel<<<NBM * NBN, 512, 0, stream>>>(A, Bt, out);
}

// Round 6
// 759.487 us; speedup vs baseline: 1.0781x; 1.0781x over previous
//
#include <hip/hip_runtime.h>
#include <hip/hip_bf16.h>

// Problem constants
#define D_IN   4096
#define D_OUT  11008
#define NB     32
#define M_ROWS 8192
#define KP     4160          // 4096 + 32 (xsum) + 32 (pad) = 65*64
#define NT     65            // K-tiles of 64

// GEMM tiling: 256x256 tile, BK=64, 8 waves (2m x 4n), 8-phase schedule
#define BM  256
#define BN  256
#define BK  64
#define NBM 32               // 8192/256
#define NBN 43               // 11008/256

typedef __attribute__((ext_vector_type(4))) float f32x4;
typedef __attribute__((ext_vector_type(8))) short bf16x8;

static __device__ __forceinline__ unsigned short f2bf(float f) {
  unsigned int u = __float_as_uint(f);
  unsigned int lsb = (u >> 16) & 1u;
  u += 0x7fffu + lsb;
  return (unsigned short)(u >> 16);
}

// ---------------------------------------------------------------------------
// Prepass A (proven): x f32 [M][4096] -> A bf16 [M][4160]
__global__ void prep_a_kernel(const float* __restrict__ x,
                              unsigned short* __restrict__ A) {
  const int m = blockIdx.x;
  const int t = threadIdx.x;
  const float* xr = x + (size_t)m * D_IN;
  unsigned short* Ar = A + (size_t)m * KP;
  __shared__ float psum[1024];
#pragma unroll
  for (int i = 0; i < 4; ++i) {
    const int c4 = i * 256 + t;
    const float4 v = ((const float4*)xr)[c4];
    ushort4 o;
    o.x = f2bf(v.x); o.y = f2bf(v.y); o.z = f2bf(v.z); o.w = f2bf(v.w);
    ((ushort4*)Ar)[c4] = o;
    psum[c4] = v.x + v.y + v.z + v.w;
  }
  __syncthreads();
  if (t < 32) {
    float s = 0.f;
    const int base = t * 32;
#pragma unroll
    for (int j = 0; j < 32; ++j) s += psum[base + j];
    Ar[D_IN + t] = f2bf(s);
  } else if (t < 64) {
    Ar[D_IN + t] = 0;
  }
}

// Prepass B (proven): w int32 [32][128][11008] -> Bt bf16 [11008][4160]
__global__ void prep_b_kernel(const int* __restrict__ w,
                              const float* __restrict__ scaler,
                              unsigned short* __restrict__ Bt) {
  const int k0 = blockIdx.x * 64;
  const int n0 = blockIdx.y * 64;
  const int s  = k0 >> 7;
  const int t  = threadIdx.x;
  __shared__ unsigned short lds[64][66];
  {
    const int nl = t & 63;
    const int kb = t >> 6;
    const float sc = scaler[(size_t)s * D_OUT + n0 + nl];
#pragma unroll
    for (int i = 0; i < 16; ++i) {
      const int kl = i * 4 + kb;
      const int wv = w[(size_t)(k0 + kl) * D_OUT + n0 + nl];
      lds[kl][nl] = f2bf((float)wv * sc);
    }
  }
  __syncthreads();
  {
    const int kl = t & 63;
    const int nb = t >> 6;
#pragma unroll
    for (int i = 0; i < 16; ++i) {
      const int nl = i * 4 + nb;
      Bt[(size_t)(n0 + nl) * KP + k0 + kl] = lds[kl][nl];
    }
  }
}

__global__ void prep_zp_kernel(const float* __restrict__ zp,
                               unsigned short* __restrict__ Bt) {
  const int t = threadIdx.x;
  const int n = blockIdx.x * 4 + (t >> 6);
  const int kk = t & 63;
  const float v = (kk < NB) ? -zp[(size_t)kk * D_OUT + n] : 0.f;
  Bt[(size_t)n * KP + D_IN + kk] = f2bf(v);
}

// ---------------------------------------------------------------------------
// 8-phase 256^2 GEMM — the proven round-2 configuration (16x16x32 MFMA, zero
// bank conflicts, plain C stores). Best measured: 705 us GEMM.
#define BAR()  __builtin_amdgcn_s_barrier()
#define PRIO1() __builtin_amdgcn_s_setprio(1)
#define PRIO0() __builtin_amdgcn_s_setprio(0)
#define VMW6() asm volatile("s_waitcnt vmcnt(6)" ::: "memory")
#define VMW8() asm volatile("s_waitcnt vmcnt(8)" ::: "memory")
#define VMW0() asm volatile("s_waitcnt vmcnt(0)" ::: "memory")

#define STQ(panelS, region, q, kb)                                             \
  do {                                                                         \
    const unsigned short* gp_ = (panelS) + (size_t)(q) * 64 * KP + (kb);       \
    unsigned short* lp_ = (region) + (q) * 4096 + (tid >> 6) * 512;            \
    __builtin_amdgcn_global_load_lds(                                          \
        (const __attribute__((address_space(1))) void*)gp_,                    \
        (__attribute__((address_space(3))) void*)lp_, 16, 0, 0);               \
  } while (0)

#define RD_AF(BUFOFF, QM)                                                      \
  do {                                                                         \
    _Pragma("unroll") for (int mf = 0; mf < 4; ++mf) {                         \
      const int ro = ((QM) * 64 + mf * 16) * 64 + (BUFOFF);                    \
      af[0][mf] = *(const bf16x8*)(smem + aOff0 + ro);                         \
      af[1][mf] = *(const bf16x8*)(smem + aOff1 + ro);                         \
    }                                                                          \
  } while (0)

#define RD_BG(BUFOFF, BG, QN)                                                  \
  do {                                                                         \
    _Pragma("unroll") for (int nf = 0; nf < 2; ++nf) {                         \
      const int ro = ((QN) * 32 + nf * 16) * 64 + 16384 + (BUFOFF);            \
      BG[0][nf] = *(const bf16x8*)(smem + bOff0 + ro);                         \
      BG[1][nf] = *(const bf16x8*)(smem + bOff1 + ro);                         \
    }                                                                          \
  } while (0)

#define MM(QM, QN, BG)                                                         \
  do {                                                                         \
    _Pragma("unroll") for (int mf = 0; mf < 4; ++mf)                           \
    _Pragma("unroll") for (int nf = 0; nf < 2; ++nf) {                         \
      f32x4 c = acc[(QM) * 4 + mf][(QN) * 2 + nf];                             \
      c = __builtin_amdgcn_mfma_f32_16x16x32_bf16(af[0][mf], BG[0][nf], c, 0, 0, 0); \
      c = __builtin_amdgcn_mfma_f32_16x16x32_bf16(af[1][mf], BG[1][nf], c, 0, 0, 0); \
      acc[(QM) * 4 + mf][(QN) * 2 + nf] = c;                                   \
    }                                                                          \
  } while (0)

__global__ __launch_bounds__(512, 2) void gemm8_kernel(
    const unsigned short* __restrict__ A,
    const unsigned short* __restrict__ B,
    float* __restrict__ C) {
  __shared__ unsigned short smem[65536];   // 128 KiB: [buf][A|B][256][64]
  const int tid  = threadIdx.x;
  const int lane = tid & 63;
  const int w    = tid >> 6;
  const int wm   = w >> 2;                 // 0..1
  const int wn   = w & 3;                  // 0..3
  const int l15  = lane & 15;
  const int g    = lane >> 4;

  // XCD-aware bijective swizzle (nwg = 1376, %8 == 0)
  const int bid = blockIdx.x;
  const int swz = (bid & 7) * ((NBM * NBN) >> 3) + (bid >> 3);
  const int tm = swz / NBN;
  const int tn = swz - tm * NBN;
  const size_t m0 = (size_t)tm * BM;
  const size_t n0 = (size_t)tn * BN;

  // Staging source: row = q*64 + (tid>>3); source granule = (tid&7)^(row&7)
  const int srow = tid >> 3;
  const int sgr  = (tid & 7) ^ (srow & 7);
  const unsigned short* ApS = A + (m0 + srow) * KP + sgr * 8;
  const unsigned short* BpS = B + (n0 + srow) * KP + sgr * 8;

  // ds_read offsets (ushort units): row*64 + swizzled-granule*8
  const int sg0 = ((g) ^ (lane & 7)) * 8;        // ks=0: granule g
  const int sg1 = ((4 + g) ^ (lane & 7)) * 8;    // ks=1: granule 4+g
  const int aOff0 = (wm * 128 + l15) * 64 + sg0;
  const int aOff1 = (wm * 128 + l15) * 64 + sg1;
  const int bOff0 = (wn * 64 + l15) * 64 + sg0;
  const int bOff1 = (wn * 64 + l15) * 64 + sg1;

  f32x4 acc[8][4];
#pragma unroll
  for (int i = 0; i < 8; ++i)
#pragma unroll
    for (int j = 0; j < 4; ++j) acc[i][j] = (f32x4){0.f, 0.f, 0.f, 0.f};
  bf16x8 af[2][4], bgA[2][2], bgB[2][2];

  // Prologue: fully stage tile 0 (buf0) then tile 1 (buf1); wait tile 0.
#pragma unroll
  for (int q = 0; q < 4; ++q) STQ(ApS, smem, q, 0);
#pragma unroll
  for (int q = 0; q < 4; ++q) STQ(BpS, smem + 16384, q, 0);
#pragma unroll
  for (int q = 0; q < 4; ++q) STQ(ApS, smem + 32768, q, 64);
#pragma unroll
  for (int q = 0; q < 4; ++q) STQ(BpS, smem + 49152, q, 64);
  VMW8();
  BAR();

#pragma unroll 1
  for (int i = 0; i < 32; ++i) {
    const int kn1 = 2 * i * 64 + 64;   // tile 2i+1 (buf1)
    const int kn2 = kn1 + 64;          // tile 2i+2 (buf0)
    const int kn3 = kn1 + 128;         // tile 2i+3 (buf1)
    const bool s3 = (i < 31);

    // P1: tile 2i Q(0,0); stage A-q1,q3 of 2i+1 -> buf1
    RD_AF(0, 0); RD_BG(0, bgA, 0);
    STQ(ApS, smem + 32768, 1, kn1); STQ(ApS, smem + 32768, 3, kn1);
    BAR(); PRIO1(); MM(0, 0, bgA); PRIO0(); BAR();

    // P2: Q(0,1); stage A-q0,q2 of 2i+2 -> buf0
    RD_BG(0, bgB, 1);
    STQ(ApS, smem, 0, kn2); STQ(ApS, smem, 2, kn2);
    BAR(); PRIO1(); MM(0, 1, bgB); PRIO0(); BAR();

    // P3: Q(1,0); stage B-q0,q1 of 2i+2 -> buf0
    RD_AF(0, 1);
    STQ(BpS, smem + 16384, 0, kn2); STQ(BpS, smem + 16384, 1, kn2);
    BAR(); PRIO1(); MM(1, 0, bgA); PRIO0(); BAR();

    // P4: Q(1,1); stage B-q2,q3 of 2i+2; vmcnt(6) -> tile 2i+1 resident
    STQ(BpS, smem + 16384, 2, kn2); STQ(BpS, smem + 16384, 3, kn2);
    BAR(); PRIO1(); MM(1, 1, bgB); PRIO0();
    VMW6(); BAR();

    // P5: tile 2i+1 (buf1) Q(0,0); stage A-q1,q3 of 2i+2 -> buf0
    RD_AF(32768, 0); RD_BG(32768, bgA, 0);
    STQ(ApS, smem, 1, kn2); STQ(ApS, smem, 3, kn2);
    BAR(); PRIO1(); MM(0, 0, bgA); PRIO0(); BAR();

    // P6: Q(0,1); stage A-q0,q2 of 2i+3 -> buf1
    RD_BG(32768, bgB, 1);
    if (s3) { STQ(ApS, smem + 32768, 0, kn3); STQ(ApS, smem + 32768, 2, kn3); }
    BAR(); PRIO1(); MM(0, 1, bgB); PRIO0(); BAR();

    // P7: Q(1,0); stage B-q0,q1 of 2i+3
    RD_AF(32768, 1);
    if (s3) { STQ(BpS, smem + 49152, 0, kn3); STQ(BpS, smem + 49152, 1, kn3); }
    BAR(); PRIO1(); MM(1, 0, bgA); PRIO0(); BAR();

    // P8: Q(1,1); stage B-q2,q3 of 2i+3; vmcnt(6) -> tile 2i+2 resident
    if (s3) { STQ(BpS, smem + 49152, 2, kn3); STQ(BpS, smem + 49152, 3, kn3); }
    BAR(); PRIO1(); MM(1, 1, bgB); PRIO0();
    VMW6(); BAR();
  }

  // Epilogue: tile 64 (buf0) — staged during last iteration; drain all.
  VMW0();
  BAR();
  RD_AF(0, 0); RD_BG(0, bgA, 0); MM(0, 0, bgA);
  RD_BG(0, bgB, 1);              MM(0, 1, bgB);
  RD_AF(0, 1);                   MM(1, 0, bgA);
                                 MM(1, 1, bgB);

  // C write: col = lane&15, row = (lane>>4)*4 + j (m89-verified layout).
#pragma unroll
  for (int mfi = 0; mfi < 8; ++mfi) {
#pragma unroll
    for (int nfi = 0; nfi < 4; ++nfi) {
      const size_t row = m0 + wm * 128 + mfi * 16 + (g << 2);
      const size_t col = n0 + wn * 64 + nfi * 16 + l15;
      float* Cp = C + row * D_OUT + col;
#pragma unroll
      for (int j = 0; j < 4; ++j) Cp[(size_t)j * D_OUT] = acc[mfi][nfi][j];
    }
  }
}

// ---------------------------------------------------------------------------
extern "C" void kernel_launch(void* const* d_in, const int* in_sizes, int n_in,
                              void* d_out, int out_size, void* d_ws, size_t ws_size,
                              hipStream_t stream) {
  const float* x      = (const float*)d_in[0];
  const int*   wq     = (const int*)  d_in[1];
  const float* scaler = (const float*)d_in[2];
  const float* zp     = (const float*)d_in[3];
  float* out = (float*)d_out;

  unsigned short* A  = (unsigned short*)d_ws;
  unsigned short* Bt = A + (size_t)M_ROWS * KP;

  prep_a_kernel<<<M_ROWS, 256, 0, stream>>>(x, A);
  prep_b_kernel<<<dim3(D_IN / 64, D_OUT / 64), 256, 0, stream>>>(wq, scaler, Bt);
  prep_zp_kernel<<<D_OUT / 4, 256, 0, stream>>>(zp, Bt);
  gemm8_kernel<<<NBM * NBN, 512, 0, stream>>>(A, Bt, out);
}